// Round 2
// baseline (183.512 us; speedup 1.0000x reference)
//
#include <hip/hip_runtime.h>

// Problem constants (from reference): B=32, I=256, J=2048, C=512, f32 in/out.
#define B_ 32
#define I_ 256
#define J_ 2048
#define C_ 512

// ---------------------------------------------------------------------------
// Kernel 1: per-sample valid lengths  L[b] = sum(text_mask[b]),
//                                    T[b] = sum(mel_mask[b]).
// Masks are JAX bools; harness converts integer-ish inputs to int32 per docs,
// but we probe the layout at runtime (first mel_mask element is guaranteed
// true since mel_len >= J/2): int32 layout -> word0 == 1; packed uint8 layout
// -> word0 == 0x01010101. Handles both without overreading either buffer.
// ---------------------------------------------------------------------------
__global__ __launch_bounds__(256)
void lengths_kernel(const void* __restrict__ text_mask,
                    const void* __restrict__ mel_mask,
                    int* __restrict__ TL /* [0..B)=L, [B..2B)=T */) {
    const int b = blockIdx.x;
    const int t = threadIdx.x;

    const unsigned int probe = ((const unsigned int*)mel_mask)[0];
    const bool packed_u8 = (probe > 1u);

    int lsum = 0, tsum = 0;
    if (packed_u8) {
        const unsigned char* tm = (const unsigned char*)text_mask;
        const unsigned char* mm = (const unsigned char*)mel_mask;
        for (int i = t; i < I_; i += blockDim.x) lsum += tm[b * I_ + i] ? 1 : 0;
        for (int j = t; j < J_; j += blockDim.x) tsum += mm[b * J_ + j] ? 1 : 0;
    } else {
        const int* tm = (const int*)text_mask;
        const int* mm = (const int*)mel_mask;
        for (int i = t; i < I_; i += blockDim.x) lsum += tm[b * I_ + i] ? 1 : 0;
        for (int j = t; j < J_; j += blockDim.x) tsum += mm[b * J_ + j] ? 1 : 0;
    }

    // wave64 butterfly reduce, then cross-wave via LDS (256 thr = 4 waves)
    for (int off = 32; off > 0; off >>= 1) {
        lsum += __shfl_down(lsum, off);
        tsum += __shfl_down(tsum, off);
    }
    __shared__ int sl[4], sm[4];
    const int wid = t >> 6;
    if ((t & 63) == 0) { sl[wid] = lsum; sm[wid] = tsum; }
    __syncthreads();
    if (t == 0) {
        TL[b]      = sl[0] + sl[1] + sl[2] + sl[3];
        TL[B_ + b] = sm[0] + sm[1] + sm[2] + sm[3];
    }
}

// ---------------------------------------------------------------------------
// Kernel 2: one block per output row (b,i); 128 threads x float4 = 512 floats.
// align_corners=False grid, op order matches reference exactly:
//   pos = (i+0.5)*Tf/Lf - 0.5 ; clip(0, Tf-1) ; i0=floor ; i1=min(i0+1,T-1)
// Padded rows (i >= L) are written as zeros (d_out is poisoned each call).
// ---------------------------------------------------------------------------
__global__ __launch_bounds__(128)
void resample_kernel(const float* __restrict__ mel,
                     const int* __restrict__ TL,
                     float* __restrict__ out) {
    const int bi = blockIdx.x;          // = b*I_ + i
    const int b  = bi >> 8;             // I_ == 256
    const int i  = bi & (I_ - 1);
    const int c4 = threadIdx.x;         // 0..127, float4 lane

    float4* orow = (float4*)(out + (size_t)bi * C_);

    const int L = TL[b];
    const int T = TL[B_ + b];

    if (i >= L) {                        // padded tail -> zeros
        orow[c4] = make_float4(0.f, 0.f, 0.f, 0.f);
        return;
    }

    const float Tf = (float)T;
    const float Lf = (float)(L > 0 ? L : 1);
    float pos = ((float)i + 0.5f) * Tf / Lf - 0.5f;
    pos = fminf(fmaxf(pos, 0.0f), Tf - 1.0f);
    int i0 = (int)floorf(pos);
    if (i0 < 0) i0 = 0;                  // safety for degenerate T
    int i1 = min(i0 + 1, T - 1);
    if (i1 < 0) i1 = 0;
    const float w  = pos - (float)i0;
    const float iw = 1.0f - w;

    const float4* g0 = (const float4*)(mel + ((size_t)b * J_ + i0) * C_);
    const float4* g1 = (const float4*)(mel + ((size_t)b * J_ + i1) * C_);
    const float4 a = g0[c4];
    const float4 v = g1[c4];

    float4 r;
    r.x = iw * a.x + w * v.x;
    r.y = iw * a.y + w * v.y;
    r.z = iw * a.z + w * v.z;
    r.w = iw * a.w + w * v.w;
    orow[c4] = r;
}

extern "C" void kernel_launch(void* const* d_in, const int* in_sizes, int n_in,
                              void* d_out, int out_size, void* d_ws, size_t ws_size,
                              hipStream_t stream) {
    // Input order per setup_inputs(): 0 mel_embeddings (f32, B*J*C),
    // 1 durations_normalized (f32, unused by reference), 2 text_mask, 3 mel_mask.
    const float* mel       = (const float*)d_in[0];
    const void*  text_mask = d_in[2];
    const void*  mel_mask  = d_in[3];
    float* out = (float*)d_out;
    int*   TL  = (int*)d_ws;            // 2*B ints of scratch

    lengths_kernel<<<B_, 256, 0, stream>>>(text_mask, mel_mask, TL);
    resample_kernel<<<B_ * I_, 128, 0, stream>>>(mel, TL, out);
}